// Round 2
// baseline (8261.518 us; speedup 1.0000x reference)
//
#include <hip/hip_runtime.h>

// Problem constants
#define HD 1024      // hidden/embed dim
#define NB 32        // batch
#define TSTEPS 127   // decode steps (T-1)
#define NV 32000     // vocab
#define MROWS 4064   // TSTEPS*NB
#define MPAD 4096    // padded to 128 multiple for GEMM

typedef __bf16 bf16x8 __attribute__((ext_vector_type(8)));
typedef float f32x4 __attribute__((ext_vector_type(4)));

__device__ __forceinline__ unsigned short f2bf(float f) {
  unsigned int u = __float_as_uint(f);
  u += 0x7FFFu + ((u >> 16) & 1u);   // round-nearest-even
  return (unsigned short)(u >> 16);
}

__device__ __forceinline__ float wred(float v) {
#pragma unroll
  for (int off = 32; off > 0; off >>= 1) v += __shfl_xor(v, off, 64);
  return v;
}

// ---------------- setup kernels ----------------
__global__ void k_init(const float* __restrict__ enc, float* __restrict__ h1,
                       float* __restrict__ h2, unsigned short* __restrict__ Abf) {
  int t = blockIdx.x * blockDim.x + threadIdx.x;  // 32768 threads
  if (t < NB * HD) {
    h1[t] = enc[t];
    h2[t] = enc[NB * HD + t];
    Abf[(size_t)MROWS * HD + t] = 0;  // zero pad rows 4064..4095
  }
}

__global__ void k_wcvt(const float4* __restrict__ src, ushort4* __restrict__ dst, int n4) {
  int stride = gridDim.x * blockDim.x;
  for (int i = blockIdx.x * blockDim.x + threadIdx.x; i < n4; i += stride) {
    float4 v = src[i];
    ushort4 o;
    o.x = f2bf(v.x); o.y = f2bf(v.y); o.z = f2bf(v.z); o.w = f2bf(v.w);
    dst[i] = o;
  }
}

// ---------------- pipelined GRU step ----------------
// Launch s: blocks [0,256) = layer1 step s (s<=126); blocks [256,512) = layer2 step s-1 (s>=1).
// Layer2 reads h1_in = h1 state AFTER step s-1 (what layer1 reads this launch) — no intra-launch dep.
__global__ __launch_bounds__(256) void k_gru(
    int s, const int* __restrict__ target, const float* __restrict__ emb,
    const float* __restrict__ Wih, const float* __restrict__ Whh,
    const float* __restrict__ bih, const float* __restrict__ bhh,
    const float* __restrict__ h1_in, float* __restrict__ h1_out,
    const float* __restrict__ h2_in, float* __restrict__ h2_out,
    unsigned short* __restrict__ Abf) {
  int blk = blockIdx.x;
  bool L2f = (blk >= 256);
  if (!L2f && s > 126) return;
  if (L2f && s < 1) return;
  int step = L2f ? (s - 1) : s;
  int wv = threadIdx.x >> 6;
  int lane = threadIdx.x & 63;
  int j = ((L2f ? blk - 256 : blk) << 2) + wv;  // hidden unit 0..1023, one per wave

  const float* Wi = Wih + (L2f ? (size_t)3 * HD * HD : 0);
  const float* Wh = Whh + (L2f ? (size_t)3 * HD * HD : 0);
  const float* bi = bih + (L2f ? 3 * HD : 0);
  const float* bh = bhh + (L2f ? 3 * HD : 0);
  const float* hin = L2f ? h2_in : h1_in;
  float* hout = L2f ? h2_out : h1_out;

  const float4* wr4 = (const float4*)(Wi + (size_t)j * HD);
  const float4* wz4 = (const float4*)(Wi + (size_t)(j + HD) * HD);
  const float4* wn4 = (const float4*)(Wi + (size_t)(j + 2 * HD) * HD);
  const float4* ur4 = (const float4*)(Wh + (size_t)j * HD);
  const float4* uz4 = (const float4*)(Wh + (size_t)(j + HD) * HD);
  const float4* un4 = (const float4*)(Wh + (size_t)(j + 2 * HD) * HD);

  float bi_r = bi[j], bi_z = bi[j + HD], bi_n = bi[j + 2 * HD];
  float bh_r = bh[j], bh_z = bh[j + HD], bh_n = bh[j + 2 * HD];

  for (int bg = 0; bg < 4; ++bg) {
    const float4* xr[8];
    const float4* hr[8];
#pragma unroll
    for (int bb = 0; bb < 8; ++bb) {
      int b = bg * 8 + bb;
      xr[bb] = L2f ? (const float4*)(h1_in + (size_t)b * HD)
                   : (const float4*)(emb + (size_t)target[b * 128 + step] * HD);
      hr[bb] = (const float4*)(hin + (size_t)b * HD);
    }
    float ar[8], az[8], ani[8], anh[8];
#pragma unroll
    for (int bb = 0; bb < 8; ++bb) { ar[bb] = 0.f; az[bb] = 0.f; ani[bb] = 0.f; anh[bb] = 0.f; }
    for (int k0 = 0; k0 < 256; k0 += 64) {  // float4 index over K=1024
      int k = k0 + lane;
      float4 w1 = wr4[k], w2 = wz4[k], w3 = wn4[k];
      float4 u1 = ur4[k], u2 = uz4[k], u3 = un4[k];
#pragma unroll
      for (int bb = 0; bb < 8; ++bb) {
        float4 xv = xr[bb][k], hv = hr[bb][k];
        ar[bb] += xv.x * w1.x + xv.y * w1.y + xv.z * w1.z + xv.w * w1.w
                + hv.x * u1.x + hv.y * u1.y + hv.z * u1.z + hv.w * u1.w;
        az[bb] += xv.x * w2.x + xv.y * w2.y + xv.z * w2.z + xv.w * w2.w
                + hv.x * u2.x + hv.y * u2.y + hv.z * u2.z + hv.w * u2.w;
        ani[bb] += xv.x * w3.x + xv.y * w3.y + xv.z * w3.z + xv.w * w3.w;
        anh[bb] += hv.x * u3.x + hv.y * u3.y + hv.z * u3.z + hv.w * u3.w;
      }
    }
#pragma unroll
    for (int bb = 0; bb < 8; ++bb) {
      ar[bb] = wred(ar[bb]); az[bb] = wred(az[bb]);
      ani[bb] = wred(ani[bb]); anh[bb] = wred(anh[bb]);
    }
    // all lanes hold all reduced sums; compile-time bb, exec-masked store (avoids
    // runtime-indexed array -> scratch, rule #20)
#pragma unroll
    for (int bb = 0; bb < 8; ++bb) {
      int b = bg * 8 + bb;
      float r = 1.f / (1.f + expf(-(ar[bb] + bi_r + bh_r)));
      float z = 1.f / (1.f + expf(-(az[bb] + bi_z + bh_z)));
      float n = tanhf(ani[bb] + bi_n + r * (anh[bb] + bh_n));
      float hv = hin[(size_t)b * HD + j];
      float hnew = (1.f - z) * n + z * hv;
      if (lane == bb) {
        hout[(size_t)b * HD + j] = hnew;
        if (L2f) Abf[((size_t)step * NB + b) * HD + j] = f2bf(hnew);
      }
    }
  }
}

// ---------------- logits GEMM: C[4064,32000] = A[4096,1024] * B[32000,1024]^T + bias ----------------
// bf16 MFMA 16x16x32; 128x128 tile, BK=64, 4 waves each 64x64 (4x4 fragments).
__global__ __launch_bounds__(256) void k_gemm(
    const unsigned short* __restrict__ A, const unsigned short* __restrict__ Bm,
    const float* __restrict__ bias, float* __restrict__ C) {
  __shared__ alignas(16) unsigned short As[128 * 64];
  __shared__ alignas(16) unsigned short Bs[128 * 64];
  int n0 = blockIdx.x * 128;
  int m0 = blockIdx.y * 128;
  int tid = threadIdx.x, lane = tid & 63, wv = tid >> 6;
  int wm = (wv >> 1) * 64, wn = (wv & 1) * 64;
  f32x4 acc[4][4];
#pragma unroll
  for (int i = 0; i < 4; ++i)
#pragma unroll
    for (int jt = 0; jt < 4; ++jt) acc[i][jt] = (f32x4){0.f, 0.f, 0.f, 0.f};

  for (int k0 = 0; k0 < 1024; k0 += 64) {
#pragma unroll
    for (int i = 0; i < 4; ++i) {
      int off = (i * 256 + tid) * 8;
      int row = off >> 6, kk = off & 63;
      *(bf16x8*)(&As[off]) = *(const bf16x8*)(&A[(size_t)(m0 + row) * HD + k0 + kk]);
      *(bf16x8*)(&Bs[off]) = *(const bf16x8*)(&Bm[(size_t)(n0 + row) * HD + k0 + kk]);
    }
    __syncthreads();
#pragma unroll
    for (int ks = 0; ks < 2; ++ks) {
      bf16x8 af[4], bfr[4];
#pragma unroll
      for (int mt = 0; mt < 4; ++mt)
        af[mt] = *(const bf16x8*)(&As[(wm + mt * 16 + (lane & 15)) * 64 + ks * 32 + (lane >> 4) * 8]);
#pragma unroll
      for (int nt = 0; nt < 4; ++nt)
        bfr[nt] = *(const bf16x8*)(&Bs[(wn + nt * 16 + (lane & 15)) * 64 + ks * 32 + (lane >> 4) * 8]);
#pragma unroll
      for (int mt = 0; mt < 4; ++mt)
#pragma unroll
        for (int nt = 0; nt < 4; ++nt)
          acc[mt][nt] = __builtin_amdgcn_mfma_f32_16x16x32_bf16(af[mt], bfr[nt], acc[mt][nt], 0, 0, 0);
    }
    __syncthreads();
  }
  // C/D layout (m89-verified): col = lane&15, row = (lane>>4)*4 + reg
#pragma unroll
  for (int nt = 0; nt < 4; ++nt) {
    int col = n0 + wn + nt * 16 + (lane & 15);
    float bv = bias[col];
#pragma unroll
    for (int mt = 0; mt < 4; ++mt) {
#pragma unroll
      for (int r = 0; r < 4; ++r) {
        int row = m0 + wm + mt * 16 + (lane >> 4) * 4 + r;
        if (row < MROWS) C[(size_t)row * NV + col] = acc[mt][nt][r] + bv;
      }
    }
  }
}

// ---------------- in-place row log_softmax over V=32000 ----------------
__global__ __launch_bounds__(1024) void k_lsm(float* __restrict__ out) {
  __shared__ float rowb[NV];  // 125 KB
  __shared__ float red[16];
  int r = blockIdx.x;
  float* p = out + (size_t)r * NV;
  int t = threadIdx.x;
  float lmax = -3.402823e38f;
  for (int i = t; i < NV; i += 1024) {
    float v = p[i];
    rowb[i] = v;
    lmax = fmaxf(lmax, v);
  }
#pragma unroll
  for (int off = 32; off > 0; off >>= 1) lmax = fmaxf(lmax, __shfl_xor(lmax, off, 64));
  if ((t & 63) == 0) red[t >> 6] = lmax;
  __syncthreads();
  if (t == 0) {
    float m = red[0];
    for (int i = 1; i < 16; ++i) m = fmaxf(m, red[i]);
    red[0] = m;
  }
  __syncthreads();
  float m = red[0];
  __syncthreads();
  float ls = 0.f;
  for (int i = t; i < NV; i += 1024) ls += expf(rowb[i] - m);
#pragma unroll
  for (int off = 32; off > 0; off >>= 1) ls += __shfl_xor(ls, off, 64);
  if ((t & 63) == 0) red[t >> 6] = ls;
  __syncthreads();
  if (t == 0) {
    float ssum = 0.f;
    for (int i = 0; i < 16; ++i) ssum += red[i];
    red[0] = m + logf(ssum);
  }
  __syncthreads();
  float L = red[0];
  for (int i = t; i < NV; i += 1024) p[i] = rowb[i] - L;
}

extern "C" void kernel_launch(void* const* d_in, const int* in_sizes, int n_in,
                              void* d_out, int out_size, void* d_ws, size_t ws_size,
                              hipStream_t stream) {
  const int* target = (const int*)d_in[0];    // [32,128] int32
  const float* enc  = (const float*)d_in[1];  // [2,32,1024]
  const float* emb  = (const float*)d_in[2];  // [32000,1024]
  const float* Wih  = (const float*)d_in[3];  // [2,3072,1024]
  const float* Whh  = (const float*)d_in[4];  // [2,3072,1024]
  const float* bih  = (const float*)d_in[5];  // [2,3072]
  const float* bhh  = (const float*)d_in[6];  // [2,3072]
  const float* outW = (const float*)d_in[7];  // [32000,1024]
  const float* outb = (const float*)d_in[8];  // [32000]
  float* out = (float*)d_out;                 // [127,32,32000]

  char* ws = (char*)d_ws;
  float* h1a = (float*)ws;                   ws += (size_t)NB * HD * 4;
  float* h1b = (float*)ws;                   ws += (size_t)NB * HD * 4;
  float* h2a = (float*)ws;                   ws += (size_t)NB * HD * 4;
  float* h2b = (float*)ws;                   ws += (size_t)NB * HD * 4;
  unsigned short* Abf = (unsigned short*)ws; ws += (size_t)MPAD * HD * 2;  // 8 MB
  unsigned short* Bbf = (unsigned short*)ws; ws += (size_t)NV * HD * 2;    // 64 MB

  k_init<<<128, 256, 0, stream>>>(enc, h1a, h2a, Abf);
  k_wcvt<<<2048, 256, 0, stream>>>((const float4*)outW, (ushort4*)Bbf, NV * HD / 4);

  float *h1c = h1a, *h1n = h1b, *h2c = h2a, *h2n = h2b;
  for (int s = 0; s < 128; ++s) {
    k_gru<<<512, 256, 0, stream>>>(s, target, emb, Wih, Whh, bih, bhh,
                                   h1c, h1n, h2c, h2n, Abf);
    if (s <= 126) { float* tmp = h1c; h1c = h1n; h1n = tmp; }
    if (s >= 1)   { float* tmp = h2c; h2c = h2n; h2n = tmp; }
  }

  k_gemm<<<dim3(NV / 128, MPAD / 128), 256, 0, stream>>>(Abf, Bbf, outb, out);
  k_lsm<<<TSTEPS * NB, 1024, 0, stream>>>(out);
}